// Round 3
// baseline (247.727 us; speedup 1.0000x reference)
//
#include <hip/hip_runtime.h>
#include <hip/hip_bf16.h>

// Fused per-type MLP chain (Linear -> ResBlock(silu,LN,Linear) -> silu-Linear -> dot)
// R3: residual x1 kept as PACKED BF16 (32 VGPRs) instead of fp32 (64 VGPRs) --
// R2 spilled res[] to scratch (VGPR_Count=84, WRITE_SIZE=54MB). k_zero replaced
// by hipMemsetAsync. Otherwise identical to R2.
// MFMA 16x16x32 bf16 layouts (HW-verified per guide m89/m91):
//   A[m][k]: m = lane&15, k = (lane>>4)*8 + j   (W row-major: contiguous 16B)
//   B[k][n]: n = lane&15, k = (lane>>4)*8 + j   (Xs row  : contiguous 16B)
//   C/D:     n(atom) = lane&15, m(neuron) = (lane>>4)*4 + reg

#define D 256
#define T 4
#define MT 64            // atoms per block
#define NTHREADS 256     // 4 waves
#define LDSTRIDE 264     // padded LDS row stride (bf16): row stride 132 dw == 4 mod 32

typedef __attribute__((ext_vector_type(8))) short bf16x8;
typedef __attribute__((ext_vector_type(4))) float f32x4;

__device__ __forceinline__ float bf2f(unsigned short s) {
    union { unsigned u; float f; } c;
    c.u = ((unsigned)s) << 16;
    return c.f;
}
__device__ __forceinline__ unsigned short f2bf(float f) {
    union { float f; unsigned u; } c;
    c.f = f;
    unsigned u = c.u;
    u += 0x7fffu + ((u >> 16) & 1u);   // round-to-nearest-even
    return (unsigned short)(u >> 16);
}
__device__ __forceinline__ unsigned pack2(float a, float b) {
    return (unsigned)f2bf(a) | ((unsigned)f2bf(b) << 16);
}
__device__ __forceinline__ float lo2f(unsigned u) { return bf2f((unsigned short)(u & 0xffffu)); }
__device__ __forceinline__ float hi2f(unsigned u) { return bf2f((unsigned short)(u >> 16)); }
__device__ __forceinline__ float silu(float v) { return v / (1.f + __expf(-v)); }

// ---------------- prep kernels ----------------

// histogram + weight fp32->bf16 convert (merged to save a launch)
extern "C" __global__ void k_hist(const int* __restrict__ species, int* counts, int N,
                                  const float* __restrict__ s0, const float* __restrict__ s1,
                                  const float* __restrict__ s2, const float* __restrict__ s3,
                                  unsigned short* __restrict__ d0, unsigned short* __restrict__ d1,
                                  unsigned short* __restrict__ d2, unsigned short* __restrict__ d3, int n4) {
    __shared__ int h[T];
    int tid = threadIdx.x;
    if (tid < T) h[tid] = 0;
    __syncthreads();
    int i = blockIdx.x * blockDim.x + tid;
    if (i < N) atomicAdd(&h[species[i]], 1);
    __syncthreads();
    if (tid < T) atomicAdd(&counts[tid], h[tid]);
    if (i < n4) {
        float4 v;
        v = ((const float4*)s0)[i];
        ((ushort4*)d0)[i] = make_ushort4(f2bf(v.x), f2bf(v.y), f2bf(v.z), f2bf(v.w));
        v = ((const float4*)s1)[i];
        ((ushort4*)d1)[i] = make_ushort4(f2bf(v.x), f2bf(v.y), f2bf(v.z), f2bf(v.w));
        v = ((const float4*)s2)[i];
        ((ushort4*)d2)[i] = make_ushort4(f2bf(v.x), f2bf(v.y), f2bf(v.z), f2bf(v.w));
        v = ((const float4*)s3)[i];
        ((ushort4*)d3)[i] = make_ushort4(f2bf(v.x), f2bf(v.y), f2bf(v.z), f2bf(v.w));
    }
}

extern "C" __global__ void k_scatter(const int* __restrict__ species, const int* __restrict__ counts,
                                     int* cursors, int* __restrict__ perm, int N) {
    __shared__ int lh[T], lbase[T];
    int tid = threadIdx.x;
    if (tid < T) lh[tid] = 0;
    __syncthreads();
    int i = blockIdx.x * blockDim.x + tid;
    int t = (i < N) ? species[i] : -1;
    int rank = 0;
    if (t >= 0) rank = atomicAdd(&lh[t], 1);
    __syncthreads();
    if (tid < T) lbase[tid] = atomicAdd(&cursors[tid], lh[tid]);
    __syncthreads();
    if (t >= 0) {
        int off = 0;
        for (int j = 0; j < t; ++j) off += counts[j];
        perm[off + lbase[t] + rank] = i;
    }
}

// ---------------- fused main kernel ----------------

extern "C" __global__ void __launch_bounds__(NTHREADS, 3)
fused_moe(const float* __restrict__ density,
          const int* __restrict__ perm,
          const int* __restrict__ counts,
          const unsigned short* __restrict__ W0b,
          const unsigned short* __restrict__ Wab,
          const unsigned short* __restrict__ Wlb,
          const unsigned short* __restrict__ Wfb,
          const float* __restrict__ b0g, const float* __restrict__ bag,
          const float* __restrict__ aag, const float* __restrict__ gg,
          const float* __restrict__ btg, const float* __restrict__ blg,
          const float* __restrict__ bfg, const float* __restrict__ afg,
          const float* __restrict__ Wog, const float* __restrict__ bog,
          float* __restrict__ out, int N)
{
    __shared__ unsigned short Xs[MT * LDSTRIDE];
    __shared__ float Pb0[D], Pba[D], Paa[D], Pg[D], Pbt[D], Pbl[D], Pbf[D], Paf[D], Pwo[D];
    __shared__ float red1[NTHREADS], red2[NTHREADS];
    __shared__ float muS[MT], rsS[MT];

    const int tid = threadIdx.x;

    // ---- which (type, tile) am I? ----
    int c[T];
#pragma unroll
    for (int i = 0; i < T; ++i) c[i] = counts[i];
    int t = -1, tile = 0, rem = blockIdx.x, off = 0;
#pragma unroll
    for (int i = 0; i < T; ++i) {
        int ti = (c[i] + MT - 1) >> 6;
        if (t < 0) {
            if (rem < ti) { t = i; tile = rem; }
            else { rem -= ti; off += c[i]; }
        }
    }
    if (t < 0) return;
    const int bstart = off + tile * MT;
    const int nrows = min(MT, c[t] - tile * MT);

    // ---- stage per-type vectors (indexed by NEURON) ----
    {
        int j = t * D + tid;
        Pb0[tid] = b0g[j]; Pba[tid] = bag[j]; Paa[tid] = aag[j];
        Pg[tid]  = gg[j];  Pbt[tid] = btg[j]; Pbl[tid] = blg[j];
        Pbf[tid] = bfg[j]; Paf[tid] = afg[j]; Pwo[tid] = Wog[j];
    }

    // ---- gather X0 (fp32 -> bf16) into LDS: Xs[atom][feature] ----
#pragma unroll
    for (int p = 0; p < 4; ++p) {
        int row = p * 16 + (tid >> 4);
        int cbase = (tid & 15) * 4;
        unsigned short* dst = Xs + row * LDSTRIDE;
        if (row < nrows) {
            const float* src = density + (size_t)perm[bstart + row] * D;
#pragma unroll
            for (int j = 0; j < 4; ++j) {
                int col = cbase + j * 64;
                float4 v = *(const float4*)(src + col);
                *(ushort4*)(dst + col) = make_ushort4(f2bf(v.x), f2bf(v.y), f2bf(v.z), f2bf(v.w));
            }
        } else {
#pragma unroll
            for (int j = 0; j < 4; ++j) {
                int col = cbase + j * 64;
                *(ushort4*)(dst + col) = make_ushort4(0, 0, 0, 0);
            }
        }
    }
    __syncthreads();

    const int lane = tid & 63;
    const int w    = tid >> 6;            // wave id -> neuron quarter
    const int ml   = lane & 15;
    const int qk   = (lane >> 4) * 8;     // A/B fragment k offset
    const int qr   = (lane >> 4) * 4;     // C/D fragment neuron offset

    const size_t wmat = (size_t)t * D * D;
    const unsigned short* W0t = W0b + wmat;
    const unsigned short* Wat = Wab + wmat;
    const unsigned short* Wlt = Wlb + wmat;
    const unsigned short* Wft = Wfb + wmat;

    f32x4 acc[4][4];
    const f32x4 zero4 = {0.f, 0.f, 0.f, 0.f};

    // D[m=neuron][n=atom]: A = W rows (global/L2), B = Xs rows (LDS)
    auto do_gemm = [&](const unsigned short* __restrict__ W) {
#pragma unroll
        for (int mi = 0; mi < 4; ++mi)
#pragma unroll
            for (int ni = 0; ni < 4; ++ni) acc[mi][ni] = zero4;
#pragma unroll
        for (int k0 = 0; k0 < D; k0 += 32) {
            bf16x8 a[4], b[4];
#pragma unroll
            for (int mi = 0; mi < 4; ++mi)
                a[mi] = *(const bf16x8*)(W + (size_t)(w * 64 + mi * 16 + ml) * D + k0 + qk);
#pragma unroll
            for (int ni = 0; ni < 4; ++ni)
                b[ni] = *(const bf16x8*)(Xs + (ni * 16 + ml) * LDSTRIDE + k0 + qk);
#pragma unroll
            for (int mi = 0; mi < 4; ++mi)
#pragma unroll
                for (int ni = 0; ni < 4; ++ni)
                    acc[mi][ni] = __builtin_amdgcn_mfma_f32_16x16x32_bf16(a[mi], b[ni], acc[mi][ni], 0, 0, 0);
        }
    };

    // lane owns atom a0 = ni*16+ml, neurons r0..r0+3 (contiguous) -> one ds_write_b64

    // ======== Layer 1: x1 = X0 @ W0^T + b0 ========
    do_gemm(W0t);
    __syncthreads();
    unsigned res[4][4][2];   // x1 saved PACKED BF16 (32 VGPRs -- no spill)
#pragma unroll
    for (int mi = 0; mi < 4; ++mi) {
#pragma unroll
        for (int ni = 0; ni < 4; ++ni) {
            int r0 = w * 64 + mi * 16 + qr;
            int a0 = ni * 16 + ml;
            float4 bb = *(const float4*)(Pb0 + r0);
            float v0 = acc[mi][ni][0] + bb.x;
            float v1 = acc[mi][ni][1] + bb.y;
            float v2 = acc[mi][ni][2] + bb.z;
            float v3 = acc[mi][ni][3] + bb.w;
            res[mi][ni][0] = pack2(v0, v1);
            res[mi][ni][1] = pack2(v2, v3);
            *(ushort4*)(Xs + a0 * LDSTRIDE + r0) =
                make_ushort4(f2bf(v0), f2bf(v1), f2bf(v2), f2bf(v3));
        }
    }
    __syncthreads();

    // ======== Layer 2: h = alpha_a * silu(x1 @ Wa^T + ba) ========
    do_gemm(Wat);
    __syncthreads();
#pragma unroll
    for (int mi = 0; mi < 4; ++mi) {
#pragma unroll
        for (int ni = 0; ni < 4; ++ni) {
            int r0 = w * 64 + mi * 16 + qr;
            int a0 = ni * 16 + ml;
            float4 bb = *(const float4*)(Pba + r0);
            float4 aa = *(const float4*)(Paa + r0);
            float v0 = aa.x * silu(acc[mi][ni][0] + bb.x);
            float v1 = aa.y * silu(acc[mi][ni][1] + bb.y);
            float v2 = aa.z * silu(acc[mi][ni][2] + bb.z);
            float v3 = aa.w * silu(acc[mi][ni][3] + bb.w);
            *(ushort4*)(Xs + a0 * LDSTRIDE + r0) =
                make_ushort4(f2bf(v0), f2bf(v1), f2bf(v2), f2bf(v3));
        }
    }
    __syncthreads();

    // ======== LayerNorm per atom over 256 neurons (in LDS) ========
    {
        int row = tid & 63, q = tid >> 6;        // conflict-free: octet spans 32 banks
        const bf16x8* base = (const bf16x8*)(Xs + row * LDSTRIDE + q * 64);
        bf16x8 hv[8];
        float sum = 0.f, ssq = 0.f;
#pragma unroll
        for (int j = 0; j < 8; ++j) {
            hv[j] = base[j];
#pragma unroll
            for (int e = 0; e < 8; ++e) {
                float f = bf2f((unsigned short)hv[j][e]);
                sum += f; ssq += f * f;
            }
        }
        red1[tid] = sum; red2[tid] = ssq;
        __syncthreads();
        if (tid < MT) {
            float s  = red1[tid] + red1[tid + 64] + red1[tid + 128] + red1[tid + 192];
            float sq = red2[tid] + red2[tid + 64] + red2[tid + 128] + red2[tid + 192];
            float mu = s * (1.f / D);
            float var = sq * (1.f / D) - mu * mu;
            muS[tid] = mu;
            rsS[tid] = rsqrtf(var + 1e-5f);
        }
        __syncthreads();
        float mu = muS[row], rs = rsS[row];
        bf16x8* wbase = (bf16x8*)(Xs + row * LDSTRIDE + q * 64);
#pragma unroll
        for (int j = 0; j < 8; ++j) {
            bf16x8 o;
#pragma unroll
            for (int e = 0; e < 8; ++e) {
                int col = q * 64 + j * 8 + e;
                float f = bf2f((unsigned short)hv[j][e]);
                o[e] = (short)f2bf(Pg[col] * (f - mu) * rs + Pbt[col]);
            }
            wbase[j] = o;
        }
    }
    __syncthreads();

    // ======== Layer 3: x3 = x1 + h @ Wl^T + bl ========
    do_gemm(Wlt);
    __syncthreads();
#pragma unroll
    for (int mi = 0; mi < 4; ++mi) {
#pragma unroll
        for (int ni = 0; ni < 4; ++ni) {
            int r0 = w * 64 + mi * 16 + qr;
            int a0 = ni * 16 + ml;
            float4 bb = *(const float4*)(Pbl + r0);
            float v0 = acc[mi][ni][0] + bb.x + lo2f(res[mi][ni][0]);
            float v1 = acc[mi][ni][1] + bb.y + hi2f(res[mi][ni][0]);
            float v2 = acc[mi][ni][2] + bb.z + lo2f(res[mi][ni][1]);
            float v3 = acc[mi][ni][3] + bb.w + hi2f(res[mi][ni][1]);
            *(ushort4*)(Xs + a0 * LDSTRIDE + r0) =
                make_ushort4(f2bf(v0), f2bf(v1), f2bf(v2), f2bf(v3));
        }
    }
    __syncthreads();

    // ======== Layer 4: x4 = alpha_f * silu(x3 @ Wf^T + bf) ========
    do_gemm(Wft);
    __syncthreads();
#pragma unroll
    for (int mi = 0; mi < 4; ++mi) {
#pragma unroll
        for (int ni = 0; ni < 4; ++ni) {
            int r0 = w * 64 + mi * 16 + qr;
            int a0 = ni * 16 + ml;
            float4 bb = *(const float4*)(Pbf + r0);
            float4 aa = *(const float4*)(Paf + r0);
            float v0 = aa.x * silu(acc[mi][ni][0] + bb.x);
            float v1 = aa.y * silu(acc[mi][ni][1] + bb.y);
            float v2 = aa.z * silu(acc[mi][ni][2] + bb.z);
            float v3 = aa.w * silu(acc[mi][ni][3] + bb.w);
            *(ushort4*)(Xs + a0 * LDSTRIDE + r0) =
                make_ushort4(f2bf(v0), f2bf(v1), f2bf(v2), f2bf(v3));
        }
    }
    __syncthreads();

    // ======== Output: y = x4 . Wo[t] + bo[t] ========
    {
        int row = tid & 63, q = tid >> 6;
        const bf16x8* base = (const bf16x8*)(Xs + row * LDSTRIDE + q * 64);
        float part = 0.f;
#pragma unroll
        for (int j = 0; j < 8; ++j) {
            bf16x8 hv = base[j];
#pragma unroll
            for (int e = 0; e < 8; ++e)
                part += bf2f((unsigned short)hv[e]) * Pwo[q * 64 + j * 8 + e];
        }
        red1[tid] = part;
        __syncthreads();
        if (tid < nrows) {
            float val = red1[tid] + red1[tid + 64] + red1[tid + 128] + red1[tid + 192] + bog[t];
            out[perm[bstart + tid]] = val;
        }
    }
}

// ---------------- launcher ----------------

extern "C" void kernel_launch(void* const* d_in, const int* in_sizes, int n_in,
                              void* d_out, int out_size, void* d_ws, size_t ws_size,
                              hipStream_t stream) {
    const float* density = (const float*)d_in[0];
    const int*   species = (const int*)d_in[1];
    const float* W0      = (const float*)d_in[2];
    const float* b0      = (const float*)d_in[3];
    const float* Wa      = (const float*)d_in[4];
    const float* ba      = (const float*)d_in[5];
    const float* alpha_a = (const float*)d_in[6];
    const float* gamma   = (const float*)d_in[7];
    const float* beta_ln = (const float*)d_in[8];
    const float* Wl      = (const float*)d_in[9];
    const float* bl      = (const float*)d_in[10];
    const float* Wf      = (const float*)d_in[11];
    const float* bfv     = (const float*)d_in[12];
    const float* alpha_f = (const float*)d_in[13];
    const float* Wo      = (const float*)d_in[14];
    const float* bo      = (const float*)d_in[15];
    float* out = (float*)d_out;
    const int N = in_sizes[1];

    char* ws = (char*)d_ws;
    int* counts  = (int*)ws;                    // T ints
    int* cursors = (int*)(ws + 16);             // T ints
    int* perm    = (int*)(ws + 64);             // N ints
    const size_t wsz = (size_t)T * D * D;       // elems per weight tensor
    unsigned short* W0b = (unsigned short*)(ws + 64 + (size_t)N * 4);
    unsigned short* Wab = W0b + wsz;
    unsigned short* Wlb = Wab + wsz;
    unsigned short* Wfb = Wlb + wsz;

    hipMemsetAsync(ws, 0, 32, stream);          // counts + cursors
    int n4 = (int)(wsz / 4);
    k_hist<<<(N + 255) / 256, 256, 0, stream>>>(species, counts, N, W0, Wa, Wl, Wf,
                                                W0b, Wab, Wlb, Wfb, n4);
    k_scatter<<<(N + 255) / 256, 256, 0, stream>>>(species, counts, cursors, perm, N);

    int nblocks = (N + MT - 1) / MT + T;
    fused_moe<<<nblocks, NTHREADS, 0, stream>>>(density, perm, counts, W0b, Wab, Wlb, Wfb,
                                                b0, ba, alpha_a, gamma, beta_ln, bl, bfv, alpha_f,
                                                Wo, bo, out, N);
}

// Round 5
// 223.605 us; speedup vs baseline: 1.1079x; 1.1079x over previous
//
#include <hip/hip_runtime.h>
#include <hip/hip_bf16.h>

// Fused per-type MLP chain (Linear -> ResBlock(silu,LN,Linear) -> silu-Linear -> dot)
// R5: STRICT BISECT from known-good R3. Single change: __launch_bounds__(256,3)
// -> (256,2) to lift the VGPR budget (~170 -> 256/wave) and eliminate the ~51MB
// scratch spill (R3: VGPR_Count=84, WRITE_SIZE=51.5MB). Everything else is
// byte-identical to R3 (passed, absmax 0.03125).
// MFMA 16x16x32 bf16 layouts (HW-verified per guide m89/m91):
//   A[m][k]: m = lane&15, k = (lane>>4)*8 + j   (W row-major: contiguous 16B)
//   B[k][n]: n = lane&15, k = (lane>>4)*8 + j   (Xs row  : contiguous 16B)
//   C/D:     n(atom) = lane&15, m(neuron) = (lane>>4)*4 + reg

#define D 256
#define T 4
#define MT 64            // atoms per block
#define NTHREADS 256     // 4 waves
#define LDSTRIDE 264     // padded LDS row stride (bf16): row stride 132 dw == 4 mod 32

typedef __attribute__((ext_vector_type(8))) short bf16x8;
typedef __attribute__((ext_vector_type(4))) float f32x4;

__device__ __forceinline__ float bf2f(unsigned short s) {
    union { unsigned u; float f; } c;
    c.u = ((unsigned)s) << 16;
    return c.f;
}
__device__ __forceinline__ unsigned short f2bf(float f) {
    union { float f; unsigned u; } c;
    c.f = f;
    unsigned u = c.u;
    u += 0x7fffu + ((u >> 16) & 1u);   // round-to-nearest-even
    return (unsigned short)(u >> 16);
}
__device__ __forceinline__ unsigned pack2(float a, float b) {
    return (unsigned)f2bf(a) | ((unsigned)f2bf(b) << 16);
}
__device__ __forceinline__ float lo2f(unsigned u) { return bf2f((unsigned short)(u & 0xffffu)); }
__device__ __forceinline__ float hi2f(unsigned u) { return bf2f((unsigned short)(u >> 16)); }
__device__ __forceinline__ float silu(float v) { return v / (1.f + __expf(-v)); }

// ---------------- prep kernels ----------------

// histogram + weight fp32->bf16 convert (merged to save a launch)
extern "C" __global__ void k_hist(const int* __restrict__ species, int* counts, int N,
                                  const float* __restrict__ s0, const float* __restrict__ s1,
                                  const float* __restrict__ s2, const float* __restrict__ s3,
                                  unsigned short* __restrict__ d0, unsigned short* __restrict__ d1,
                                  unsigned short* __restrict__ d2, unsigned short* __restrict__ d3, int n4) {
    __shared__ int h[T];
    int tid = threadIdx.x;
    if (tid < T) h[tid] = 0;
    __syncthreads();
    int i = blockIdx.x * blockDim.x + tid;
    if (i < N) atomicAdd(&h[species[i]], 1);
    __syncthreads();
    if (tid < T) atomicAdd(&counts[tid], h[tid]);
    if (i < n4) {
        float4 v;
        v = ((const float4*)s0)[i];
        ((ushort4*)d0)[i] = make_ushort4(f2bf(v.x), f2bf(v.y), f2bf(v.z), f2bf(v.w));
        v = ((const float4*)s1)[i];
        ((ushort4*)d1)[i] = make_ushort4(f2bf(v.x), f2bf(v.y), f2bf(v.z), f2bf(v.w));
        v = ((const float4*)s2)[i];
        ((ushort4*)d2)[i] = make_ushort4(f2bf(v.x), f2bf(v.y), f2bf(v.z), f2bf(v.w));
        v = ((const float4*)s3)[i];
        ((ushort4*)d3)[i] = make_ushort4(f2bf(v.x), f2bf(v.y), f2bf(v.z), f2bf(v.w));
    }
}

extern "C" __global__ void k_scatter(const int* __restrict__ species, const int* __restrict__ counts,
                                     int* cursors, int* __restrict__ perm, int N) {
    __shared__ int lh[T], lbase[T];
    int tid = threadIdx.x;
    if (tid < T) lh[tid] = 0;
    __syncthreads();
    int i = blockIdx.x * blockDim.x + tid;
    int t = (i < N) ? species[i] : -1;
    int rank = 0;
    if (t >= 0) rank = atomicAdd(&lh[t], 1);
    __syncthreads();
    if (tid < T) lbase[tid] = atomicAdd(&cursors[tid], lh[tid]);
    __syncthreads();
    if (t >= 0) {
        int off = 0;
        for (int j = 0; j < t; ++j) off += counts[j];
        perm[off + lbase[t] + rank] = i;
    }
}

// ---------------- fused main kernel ----------------

extern "C" __global__ void __launch_bounds__(NTHREADS, 2)
fused_moe(const float* __restrict__ density,
          const int* __restrict__ perm,
          const int* __restrict__ counts,
          const unsigned short* __restrict__ W0b,
          const unsigned short* __restrict__ Wab,
          const unsigned short* __restrict__ Wlb,
          const unsigned short* __restrict__ Wfb,
          const float* __restrict__ b0g, const float* __restrict__ bag,
          const float* __restrict__ aag, const float* __restrict__ gg,
          const float* __restrict__ btg, const float* __restrict__ blg,
          const float* __restrict__ bfg, const float* __restrict__ afg,
          const float* __restrict__ Wog, const float* __restrict__ bog,
          float* __restrict__ out, int N)
{
    __shared__ unsigned short Xs[MT * LDSTRIDE];
    __shared__ float Pb0[D], Pba[D], Paa[D], Pg[D], Pbt[D], Pbl[D], Pbf[D], Paf[D], Pwo[D];
    __shared__ float red1[NTHREADS], red2[NTHREADS];
    __shared__ float muS[MT], rsS[MT];

    const int tid = threadIdx.x;

    // ---- which (type, tile) am I? ----
    int c[T];
#pragma unroll
    for (int i = 0; i < T; ++i) c[i] = counts[i];
    int t = -1, tile = 0, rem = blockIdx.x, off = 0;
#pragma unroll
    for (int i = 0; i < T; ++i) {
        int ti = (c[i] + MT - 1) >> 6;
        if (t < 0) {
            if (rem < ti) { t = i; tile = rem; }
            else { rem -= ti; off += c[i]; }
        }
    }
    if (t < 0) return;
    const int bstart = off + tile * MT;
    const int nrows = min(MT, c[t] - tile * MT);

    // ---- stage per-type vectors (indexed by NEURON) ----
    {
        int j = t * D + tid;
        Pb0[tid] = b0g[j]; Pba[tid] = bag[j]; Paa[tid] = aag[j];
        Pg[tid]  = gg[j];  Pbt[tid] = btg[j]; Pbl[tid] = blg[j];
        Pbf[tid] = bfg[j]; Paf[tid] = afg[j]; Pwo[tid] = Wog[j];
    }

    // ---- gather X0 (fp32 -> bf16) into LDS: Xs[atom][feature] ----
#pragma unroll
    for (int p = 0; p < 4; ++p) {
        int row = p * 16 + (tid >> 4);
        int cbase = (tid & 15) * 4;
        unsigned short* dst = Xs + row * LDSTRIDE;
        if (row < nrows) {
            const float* src = density + (size_t)perm[bstart + row] * D;
#pragma unroll
            for (int j = 0; j < 4; ++j) {
                int col = cbase + j * 64;
                float4 v = *(const float4*)(src + col);
                *(ushort4*)(dst + col) = make_ushort4(f2bf(v.x), f2bf(v.y), f2bf(v.z), f2bf(v.w));
            }
        } else {
#pragma unroll
            for (int j = 0; j < 4; ++j) {
                int col = cbase + j * 64;
                *(ushort4*)(dst + col) = make_ushort4(0, 0, 0, 0);
            }
        }
    }
    __syncthreads();

    const int lane = tid & 63;
    const int w    = tid >> 6;            // wave id -> neuron quarter
    const int ml   = lane & 15;
    const int qk   = (lane >> 4) * 8;     // A/B fragment k offset
    const int qr   = (lane >> 4) * 4;     // C/D fragment neuron offset

    const size_t wmat = (size_t)t * D * D;
    const unsigned short* W0t = W0b + wmat;
    const unsigned short* Wat = Wab + wmat;
    const unsigned short* Wlt = Wlb + wmat;
    const unsigned short* Wft = Wfb + wmat;

    f32x4 acc[4][4];
    const f32x4 zero4 = {0.f, 0.f, 0.f, 0.f};

    // D[m=neuron][n=atom]: A = W rows (global/L2), B = Xs rows (LDS)
    auto do_gemm = [&](const unsigned short* __restrict__ W) {
#pragma unroll
        for (int mi = 0; mi < 4; ++mi)
#pragma unroll
            for (int ni = 0; ni < 4; ++ni) acc[mi][ni] = zero4;
#pragma unroll
        for (int k0 = 0; k0 < D; k0 += 32) {
            bf16x8 a[4], b[4];
#pragma unroll
            for (int mi = 0; mi < 4; ++mi)
                a[mi] = *(const bf16x8*)(W + (size_t)(w * 64 + mi * 16 + ml) * D + k0 + qk);
#pragma unroll
            for (int ni = 0; ni < 4; ++ni)
                b[ni] = *(const bf16x8*)(Xs + (ni * 16 + ml) * LDSTRIDE + k0 + qk);
#pragma unroll
            for (int mi = 0; mi < 4; ++mi)
#pragma unroll
                for (int ni = 0; ni < 4; ++ni)
                    acc[mi][ni] = __builtin_amdgcn_mfma_f32_16x16x32_bf16(a[mi], b[ni], acc[mi][ni], 0, 0, 0);
        }
    };

    // lane owns atom a0 = ni*16+ml, neurons r0..r0+3 (contiguous) -> one ds_write_b64

    // ======== Layer 1: x1 = X0 @ W0^T + b0 ========
    do_gemm(W0t);
    __syncthreads();
    unsigned res[4][4][2];   // x1 saved PACKED BF16 (32 VGPRs)
#pragma unroll
    for (int mi = 0; mi < 4; ++mi) {
#pragma unroll
        for (int ni = 0; ni < 4; ++ni) {
            int r0 = w * 64 + mi * 16 + qr;
            int a0 = ni * 16 + ml;
            float4 bb = *(const float4*)(Pb0 + r0);
            float v0 = acc[mi][ni][0] + bb.x;
            float v1 = acc[mi][ni][1] + bb.y;
            float v2 = acc[mi][ni][2] + bb.z;
            float v3 = acc[mi][ni][3] + bb.w;
            res[mi][ni][0] = pack2(v0, v1);
            res[mi][ni][1] = pack2(v2, v3);
            *(ushort4*)(Xs + a0 * LDSTRIDE + r0) =
                make_ushort4(f2bf(v0), f2bf(v1), f2bf(v2), f2bf(v3));
        }
    }
    __syncthreads();

    // ======== Layer 2: h = alpha_a * silu(x1 @ Wa^T + ba) ========
    do_gemm(Wat);
    __syncthreads();
#pragma unroll
    for (int mi = 0; mi < 4; ++mi) {
#pragma unroll
        for (int ni = 0; ni < 4; ++ni) {
            int r0 = w * 64 + mi * 16 + qr;
            int a0 = ni * 16 + ml;
            float4 bb = *(const float4*)(Pba + r0);
            float4 aa = *(const float4*)(Paa + r0);
            float v0 = aa.x * silu(acc[mi][ni][0] + bb.x);
            float v1 = aa.y * silu(acc[mi][ni][1] + bb.y);
            float v2 = aa.z * silu(acc[mi][ni][2] + bb.z);
            float v3 = aa.w * silu(acc[mi][ni][3] + bb.w);
            *(ushort4*)(Xs + a0 * LDSTRIDE + r0) =
                make_ushort4(f2bf(v0), f2bf(v1), f2bf(v2), f2bf(v3));
        }
    }
    __syncthreads();

    // ======== LayerNorm per atom over 256 neurons (in LDS) ========
    {
        int row = tid & 63, q = tid >> 6;        // conflict-free: octet spans 32 banks
        const bf16x8* base = (const bf16x8*)(Xs + row * LDSTRIDE + q * 64);
        bf16x8 hv[8];
        float sum = 0.f, ssq = 0.f;
#pragma unroll
        for (int j = 0; j < 8; ++j) {
            hv[j] = base[j];
#pragma unroll
            for (int e = 0; e < 8; ++e) {
                float f = bf2f((unsigned short)hv[j][e]);
                sum += f; ssq += f * f;
            }
        }
        red1[tid] = sum; red2[tid] = ssq;
        __syncthreads();
        if (tid < MT) {
            float s  = red1[tid] + red1[tid + 64] + red1[tid + 128] + red1[tid + 192];
            float sq = red2[tid] + red2[tid + 64] + red2[tid + 128] + red2[tid + 192];
            float mu = s * (1.f / D);
            float var = sq * (1.f / D) - mu * mu;
            muS[tid] = mu;
            rsS[tid] = rsqrtf(var + 1e-5f);
        }
        __syncthreads();
        float mu = muS[row], rs = rsS[row];
        bf16x8* wbase = (bf16x8*)(Xs + row * LDSTRIDE + q * 64);
#pragma unroll
        for (int j = 0; j < 8; ++j) {
            bf16x8 o;
#pragma unroll
            for (int e = 0; e < 8; ++e) {
                int col = q * 64 + j * 8 + e;
                float f = bf2f((unsigned short)hv[j][e]);
                o[e] = (short)f2bf(Pg[col] * (f - mu) * rs + Pbt[col]);
            }
            wbase[j] = o;
        }
    }
    __syncthreads();

    // ======== Layer 3: x3 = x1 + h @ Wl^T + bl ========
    do_gemm(Wlt);
    __syncthreads();
#pragma unroll
    for (int mi = 0; mi < 4; ++mi) {
#pragma unroll
        for (int ni = 0; ni < 4; ++ni) {
            int r0 = w * 64 + mi * 16 + qr;
            int a0 = ni * 16 + ml;
            float4 bb = *(const float4*)(Pbl + r0);
            float v0 = acc[mi][ni][0] + bb.x + lo2f(res[mi][ni][0]);
            float v1 = acc[mi][ni][1] + bb.y + hi2f(res[mi][ni][0]);
            float v2 = acc[mi][ni][2] + bb.z + lo2f(res[mi][ni][1]);
            float v3 = acc[mi][ni][3] + bb.w + hi2f(res[mi][ni][1]);
            *(ushort4*)(Xs + a0 * LDSTRIDE + r0) =
                make_ushort4(f2bf(v0), f2bf(v1), f2bf(v2), f2bf(v3));
        }
    }
    __syncthreads();

    // ======== Layer 4: x4 = alpha_f * silu(x3 @ Wf^T + bf) ========
    do_gemm(Wft);
    __syncthreads();
#pragma unroll
    for (int mi = 0; mi < 4; ++mi) {
#pragma unroll
        for (int ni = 0; ni < 4; ++ni) {
            int r0 = w * 64 + mi * 16 + qr;
            int a0 = ni * 16 + ml;
            float4 bb = *(const float4*)(Pbf + r0);
            float4 aa = *(const float4*)(Paf + r0);
            float v0 = aa.x * silu(acc[mi][ni][0] + bb.x);
            float v1 = aa.y * silu(acc[mi][ni][1] + bb.y);
            float v2 = aa.z * silu(acc[mi][ni][2] + bb.z);
            float v3 = aa.w * silu(acc[mi][ni][3] + bb.w);
            *(ushort4*)(Xs + a0 * LDSTRIDE + r0) =
                make_ushort4(f2bf(v0), f2bf(v1), f2bf(v2), f2bf(v3));
        }
    }
    __syncthreads();

    // ======== Output: y = x4 . Wo[t] + bo[t] ========
    {
        int row = tid & 63, q = tid >> 6;
        const bf16x8* base = (const bf16x8*)(Xs + row * LDSTRIDE + q * 64);
        float part = 0.f;
#pragma unroll
        for (int j = 0; j < 8; ++j) {
            bf16x8 hv = base[j];
#pragma unroll
            for (int e = 0; e < 8; ++e)
                part += bf2f((unsigned short)hv[e]) * Pwo[q * 64 + j * 8 + e];
        }
        red1[tid] = part;
        __syncthreads();
        if (tid < nrows) {
            float val = red1[tid] + red1[tid + 64] + red1[tid + 128] + red1[tid + 192] + bog[t];
            out[perm[bstart + tid]] = val;
        }
    }
}

// ---------------- launcher ----------------

extern "C" void kernel_launch(void* const* d_in, const int* in_sizes, int n_in,
                              void* d_out, int out_size, void* d_ws, size_t ws_size,
                              hipStream_t stream) {
    const float* density = (const float*)d_in[0];
    const int*   species = (const int*)d_in[1];
    const float* W0      = (const float*)d_in[2];
    const float* b0      = (const float*)d_in[3];
    const float* Wa      = (const float*)d_in[4];
    const float* ba      = (const float*)d_in[5];
    const float* alpha_a = (const float*)d_in[6];
    const float* gamma   = (const float*)d_in[7];
    const float* beta_ln = (const float*)d_in[8];
    const float* Wl      = (const float*)d_in[9];
    const float* bl      = (const float*)d_in[10];
    const float* Wf      = (const float*)d_in[11];
    const float* bfv     = (const float*)d_in[12];
    const float* alpha_f = (const float*)d_in[13];
    const float* Wo      = (const float*)d_in[14];
    const float* bo      = (const float*)d_in[15];
    float* out = (float*)d_out;
    const int N = in_sizes[1];

    char* ws = (char*)d_ws;
    int* counts  = (int*)ws;                    // T ints
    int* cursors = (int*)(ws + 16);             // T ints
    int* perm    = (int*)(ws + 64);             // N ints
    const size_t wsz = (size_t)T * D * D;       // elems per weight tensor
    unsigned short* W0b = (unsigned short*)(ws + 64 + (size_t)N * 4);
    unsigned short* Wab = W0b + wsz;
    unsigned short* Wlb = Wab + wsz;
    unsigned short* Wfb = Wlb + wsz;

    hipMemsetAsync(ws, 0, 32, stream);          // counts + cursors
    int n4 = (int)(wsz / 4);
    k_hist<<<(N + 255) / 256, 256, 0, stream>>>(species, counts, N, W0, Wa, Wl, Wf,
                                                W0b, Wab, Wlb, Wfb, n4);
    k_scatter<<<(N + 255) / 256, 256, 0, stream>>>(species, counts, cursors, perm, N);

    int nblocks = (N + MT - 1) / MT + T;
    fused_moe<<<nblocks, NTHREADS, 0, stream>>>(density, perm, counts, W0b, Wab, Wlb, Wfb,
                                                b0, ba, alpha_a, gamma, beta_ln, bl, bfv, alpha_f,
                                                Wo, bo, out, N);
}